// Round 4
// baseline (254.164 us; speedup 1.0000x reference)
//
#include <hip/hip_runtime.h>

// shift op: out[b, g*32+c, h, w] = x[b, g*32+c, h+dh, w+dw] (zero outside),
// groups g=0..7; channels 256..287 stay zero.  (32, 288, 64, 64) fp32.
// Pure streaming: 134 MB read + 151 MB write -> ~43 us floor @ 6.6 TB/s.
//
// 1 block per (b,c) plane, 256 threads, 4 float4 per thread (4 row-slabs,
// unrolled -> 4 independent load/store chains in flight). All loads/stores
// are aligned dwordx4; the w+-1 shift comes from one cross-lane __shfl
// (lane+1 holds the next float4 of the same row). Nontemporal stores:
// output is write-once, keep it from evicting the LLC-resident input.
// NOTE: __builtin_nontemporal_store needs a clang ext_vector_type, not
// HIP's float4 class -> use v4f.

#define CC  288
#define HH  64
#define WW  64

typedef float v4f __attribute__((ext_vector_type(4)));

__global__ __launch_bounds__(256) void shift_kernel(const float* __restrict__ x,
                                                    float* __restrict__ out) {
    const int plane = blockIdx.x;            // b*C + c   (0..9215)
    const int c     = plane % CC;
    const int g     = c >> 5;                // c / 32

    const int t  = threadIdx.x;              // 0..255
    const int w0 = (t & 15) << 2;            // 0,4,...,60
    const int h0 = t >> 4;                   // 0..15

    float* __restrict__       outp = out + (size_t)plane * (HH * WW);
    const float* __restrict__ xp   = x   + (size_t)plane * (HH * WW);

    const v4f zero = (v4f){0.f, 0.f, 0.f, 0.f};

    if (g >= 8) {                            // group 8: stays zero
        #pragma unroll
        for (int q = 0; q < 4; ++q)
            __builtin_nontemporal_store(zero, (v4f*)(outp + (h0 + 16 * q) * WW + w0));
        return;
    }

    // offsets: g0(-1,0) g1(1,0) g2(0,-1) g3(0,1) g4(-1,-1) g5(-1,1) g6(1,-1) g7(1,1)
    const int dh = (int)((0x22001120u >> (g * 4)) & 0xFu) - 1;
    const int dw = (int)((0x20202011u >> (g * 4)) & 0xFu) - 1;
    const int lane = t & 63;

    #pragma unroll
    for (int q = 0; q < 4; ++q) {
        const int h  = h0 + 16 * q;
        const int hs = h + dh;
        v4f v;
        if ((unsigned)hs >= (unsigned)HH) {  // source row out of bounds -> zero
            v = zero;
        } else {
            const float* __restrict__ row = xp + hs * WW;
            v4f a = *(const v4f*)(row + w0);       // single aligned 16B load
            if (dw == 0) {
                v = a;
            } else if (dw == 1) {
                // out[w] = row[w+1]; row[w0+4] == lane+1's a.x (rows span 16 lanes)
                float nx = __shfl(a.x, lane + 1);
                v.x = a.y; v.y = a.z; v.z = a.w;
                v.w = (w0 == 60) ? 0.f : nx;       // row edge -> zero
            } else {
                // out[w] = row[w-1]; row[w0-1] == lane-1's a.w
                float pw = __shfl(a.w, lane - 1);
                v.x = (w0 == 0) ? 0.f : pw;
                v.y = a.x; v.z = a.y; v.w = a.z;
            }
        }
        __builtin_nontemporal_store(v, (v4f*)(outp + h * WW + w0));
    }
}

extern "C" void kernel_launch(void* const* d_in, const int* in_sizes, int n_in,
                              void* d_out, int out_size, void* d_ws, size_t ws_size,
                              hipStream_t stream) {
    const float* x = (const float*)d_in[0];
    float* out = (float*)d_out;
    // 1 block per (b,c) plane; 256 threads x 4 float4 = 4096 floats = 64x64
    shift_kernel<<<dim3(32 * CC), dim3(256), 0, stream>>>(x, out);
}